// Round 1
// baseline (188.396 us; speedup 1.0000x reference)
//
#include <hip/hip_runtime.h>
#include <hip/hip_bf16.h>
#include <stdint.h>

typedef unsigned short ushort_t;
typedef short v8s __attribute__((ext_vector_type(8)));
typedef float f32x4 __attribute__((ext_vector_type(4)));

#define MFMA16(a, b, c) __builtin_amdgcn_mfma_f32_16x16x32_bf16(a, b, c, 0, 0, 0)

typedef __attribute__((address_space(1))) void gvoid;
typedef __attribute__((address_space(3))) void svoid;

__device__ __forceinline__ void gld16(const void* g, void* s) {
    // async global->LDS, 16B per lane; LDS dest = wave-uniform base + lane*16
    __builtin_amdgcn_global_load_lds((gvoid*)g, (svoid*)s, 16, 0, 0);
}

__device__ __forceinline__ ushort_t f2bf(float f) {
    union { __hip_bfloat16 b; ushort_t u; } c;
    c.b = __float2bfloat16(f);
    return c.u;
}

__device__ __forceinline__ unsigned f2bf2(float a, float b) {
    union { __hip_bfloat162 b2; unsigned u; } c;
    c.b2 = __float22bfloat162_rn(make_float2(a, b));
    return c.u;
}

// ---------------------------------------------------------------------------
// Kernel 1: transpose W [2048][128] f32 -> WT [3][128][2048] bf16
// ---------------------------------------------------------------------------
__global__ void transpose_w(const float* __restrict__ Wq, const float* __restrict__ Wk,
                            const float* __restrict__ Wv, ushort_t* __restrict__ WT) {
    __shared__ float tile[64][132];  // +4 pad breaks column-read conflicts
    int bid = blockIdx.x;            // 96 = 3 weights x 32 k-blocks
    int w = bid >> 5;
    int k0 = (bid & 31) << 6;
    const float* W = (w == 0) ? Wq : ((w == 1) ? Wk : Wv);
    int tid = threadIdx.x;
    #pragma unroll
    for (int i = 0; i < 8; i++) {
        int row = i * 8 + (tid >> 5);
        int col = (tid & 31) * 4;
        float4 v = *(const float4*)(W + (size_t)(k0 + row) * 128 + col);
        tile[row][col] = v.x; tile[row][col + 1] = v.y;
        tile[row][col + 2] = v.z; tile[row][col + 3] = v.w;
    }
    __syncthreads();
    int n = tid >> 1, kh = (tid & 1) * 32;
    ushort_t* dst = WT + ((size_t)(w * 128 + n)) * 2048 + k0 + kh;
    #pragma unroll
    for (int j = 0; j < 32; j += 4) {
        union { ushort_t u[4]; uint2 v2; } pk;
        #pragma unroll
        for (int e = 0; e < 4; e++) pk.u[e] = f2bf(tile[kh + j + e][n]);
        *(uint2*)(dst + j) = pk.v2;
    }
}

// ---------------------------------------------------------------------------
// Kernel 2: QKV projection. x[16384][2048] f32 * WT[w][128][2048] bf16
//   -> w=0: q row-major bf16 [16384][128]
//   -> w=1: k_blk  [b][t/16][d/8][t%16][d%8]  (B-fragment friendly)
//   -> w=2: v_blk  [b][t/8][d][t%8]           (B-fragment friendly)
// grid 384 = 16 groups * (8 mtiles x 3 w)  (same-mtile blocks land on same XCD)
// ---------------------------------------------------------------------------
__launch_bounds__(256, 2)
__global__ void proj_kernel(const float* __restrict__ x, const ushort_t* __restrict__ WT,
                            ushort_t* __restrict__ q, ushort_t* __restrict__ kb,
                            ushort_t* __restrict__ vb) {
    __shared__ float    abuf[8192];   // [128 m][64 k] f32, byte-swizzle ^((row&7)<<5)
    __shared__ ushort_t bbuf[8192];   // [128 n][64 k] bf16, byte-swizzle ^((row&7)<<4)

    int bid = blockIdx.x;
    int g24 = bid / 24, r24 = bid % 24;
    int mt = g24 * 8 + (r24 & 7);
    int w = r24 >> 3;
    long m0 = (long)mt * 128;
    int tid = threadIdx.x;
    int lane = tid & 63, wid = tid >> 6;
    int lg = lane >> 4, lr = lane & 15;
    int wm0 = (wid >> 1) * 64, wn0 = (wid & 1) * 64;

    f32x4 acc[4][4];
    #pragma unroll
    for (int i = 0; i < 4; i++)
        #pragma unroll
        for (int j = 0; j < 4; j++) acc[i][j] = f32x4{0.f, 0.f, 0.f, 0.f};

    const char* wtw = (const char*)(WT + (size_t)w * 128 * 2048);
    const char* xb = (const char*)x;

    for (int it = 0; it < 32; ++it) {
        if (it) __syncthreads();
        // stage x tile [128][64] f32 (32KB, 32 segs), pre-swizzled source
        #pragma unroll
        for (int i = 0; i < 8; i++) {
            int seg = i * 4 + wid;
            int o = seg * 1024 + lane * 16;
            int row = o >> 8;
            int col = (o & 255) ^ ((row & 7) << 5);
            gld16(xb + ((m0 + row) * 2048 + it * 64) * 4 + col, (char*)abuf + seg * 1024);
        }
        // stage WT tile [128][64] bf16 (16KB, 16 segs)
        #pragma unroll
        for (int i = 0; i < 4; i++) {
            int seg = i * 4 + wid;
            int o = seg * 1024 + lane * 16;
            int row = o >> 7;
            int col = (o & 127) ^ ((row & 7) << 4);
            gld16(wtw + (row * 2048 + it * 64) * 2 + col, (char*)bbuf + seg * 1024);
        }
        __syncthreads();

        v8s af[4][2], bf[4][2];
        #pragma unroll
        for (int m = 0; m < 4; m++) {
            int row = wm0 + m * 16 + lr;
            #pragma unroll
            for (int kk = 0; kk < 2; kk++) {
                int byte_off = (kk * 128 + lg * 32) ^ ((row & 7) << 5);
                const float* p = (const float*)((const char*)abuf + row * 256 + byte_off);
                float4 x0 = *(const float4*)p;
                float4 x1 = *(const float4*)(p + 4);
                union { v8s v; unsigned u[4]; } pk;
                pk.u[0] = f2bf2(x0.x, x0.y);
                pk.u[1] = f2bf2(x0.z, x0.w);
                pk.u[2] = f2bf2(x1.x, x1.y);
                pk.u[3] = f2bf2(x1.z, x1.w);
                af[m][kk] = pk.v;
            }
        }
        #pragma unroll
        for (int n = 0; n < 4; n++) {
            int row = wn0 + n * 16 + lr;
            #pragma unroll
            for (int kk = 0; kk < 2; kk++) {
                int byte_off = (kk * 64 + lg * 16) ^ ((row & 7) << 4);
                bf[n][kk] = *(const v8s*)((const char*)bbuf + row * 128 + byte_off);
            }
        }
        #pragma unroll
        for (int m = 0; m < 4; m++)
            #pragma unroll
            for (int n = 0; n < 4; n++)
                #pragma unroll
                for (int kk = 0; kk < 2; kk++)
                    acc[m][n] = MFMA16(af[m][kk], bf[n][kk], acc[m][n]);
    }

    // epilogue: D-layout lane holds row=4*lg+r, col=lr (within 16x16 tile)
    #pragma unroll
    for (int m = 0; m < 4; m++) {
        #pragma unroll
        for (int r = 0; r < 4; r++) {
            long trow = m0 + wm0 + m * 16 + 4 * lg + r;
            if (w == 0) {
                ushort_t* orow = q + (size_t)trow * 128 + wn0 + lr;
                #pragma unroll
                for (int n = 0; n < 4; n++) orow[n * 16] = f2bf(acc[m][n][r]);
            } else if (w == 1) {
                int bb = (int)(trow >> 12), t = (int)(trow & 4095);
                ushort_t* ob = kb + ((size_t)(bb * 256 + (t >> 4))) * 2048 + (t & 15) * 8;
                #pragma unroll
                for (int n = 0; n < 4; n++) {
                    int d = wn0 + n * 16 + lr;
                    ob[(d >> 3) * 128 + (d & 7)] = f2bf(acc[m][n][r]);
                }
            } else {
                int bb = (int)(trow >> 12), t = (int)(trow & 4095);
                ushort_t* ob = vb + ((size_t)(bb * 512 + (t >> 3))) * 1024 + (t & 7);
                #pragma unroll
                for (int n = 0; n < 4; n++) {
                    int d = wn0 + n * 16 + lr;
                    ob[d * 8] = f2bf(acc[m][n][r]);
                }
            }
        }
    }
}

// ---------------------------------------------------------------------------
// Kernel 3: causal flash attention. 512 blocks (4 batch x 128 qtiles, longest
// first), 2 waves/block, 16 q-rows/wave, KVBLK=64. K/V staged as linear 16KB
// contiguous chunks (blocked layouts), online softmax in registers.
// ---------------------------------------------------------------------------
__launch_bounds__(128, 2)
__global__ void attn_kernel(const ushort_t* __restrict__ q, const ushort_t* __restrict__ kb,
                            const ushort_t* __restrict__ vb, float* __restrict__ out) {
    __shared__ ushort_t kbuf[8192];    // [4 tb][16 dblk][16 tl][8 dl]
    __shared__ ushort_t vbuf[8192];    // [8 tb8][128 d][8 tl]
    __shared__ ushort_t pbuf[2][1024]; // per wave: [8 kvblk][16 q][8 kv]

    int bid = blockIdx.x;
    int b = bid & 3;
    int qtile = 127 - (bid >> 2);   // longest-first dispatch
    int qt0 = qtile * 32;
    int tid = threadIdx.x, lane = tid & 63, wid = tid >> 6;
    int lg = lane >> 4, lr = lane & 15;

    // Q fragments for this wave's 16 rows (read direct from global, coalesced)
    v8s qf[4];
    {
        const ushort_t* qrow = q + ((size_t)(b * 4096 + qt0 + wid * 16 + lr)) * 128;
        #pragma unroll
        for (int kk = 0; kk < 4; kk++)
            qf[kk] = *(const v8s*)(qrow + kk * 32 + lg * 8);
    }

    f32x4 accO[8];
    #pragma unroll
    for (int i = 0; i < 8; i++) accO[i] = f32x4{0.f, 0.f, 0.f, 0.f};
    float mrun[4], lrun[4];
    #pragma unroll
    for (int r = 0; r < 4; r++) { mrun[r] = -1e30f; lrun[r] = 0.f; }

    int ntiles = ((qt0 + 31) >> 6) + 1;
    const float cexp = 0.08838834764831845f * 1.4426950408889634f;  // scale*log2e

    for (int t = 0; t < ntiles; ++t) {
        if (t) __syncthreads();
        {   // stage K (16KB) + V (16KB), both linear contiguous
            const char* kg = (const char*)(kb + ((size_t)(b * 256 + t * 4)) * 2048);
            const char* vg = (const char*)(vb + ((size_t)(b * 512 + t * 8)) * 1024);
            #pragma unroll
            for (int i = 0; i < 8; i++) {
                int seg = i * 2 + wid;
                gld16(kg + seg * 1024 + lane * 16, (char*)kbuf + seg * 1024);
                gld16(vg + seg * 1024 + lane * 16, (char*)vbuf + seg * 1024);
            }
        }
        __syncthreads();

        // S = Q K^T  (4 n-tiles of 16 kv, K-loop over d in 4 steps)
        f32x4 s[4];
        #pragma unroll
        for (int nt = 0; nt < 4; nt++) {
            s[nt] = f32x4{0.f, 0.f, 0.f, 0.f};
            #pragma unroll
            for (int kk = 0; kk < 4; kk++) {
                v8s kf = *(const v8s*)(kbuf + nt * 2048 + (kk * 4 + lg) * 128 + lr * 8);
                s[nt] = MFMA16(qf[kk], kf, s[nt]);
            }
        }

        // causal mask on diagonal tile
        if (t == ntiles - 1) {
            int qrow = qt0 + wid * 16 + 4 * lg;
            #pragma unroll
            for (int nt = 0; nt < 4; nt++) {
                int kv = t * 64 + nt * 16 + lr;
                #pragma unroll
                for (int r = 0; r < 4; r++)
                    if (kv > qrow + r) s[nt][r] = -1e30f;
            }
        }

        // online softmax: row stats live in 16-lane groups (rows 4*lg+r)
        float mx[4];
        #pragma unroll
        for (int r = 0; r < 4; r++)
            mx[r] = fmaxf(fmaxf(s[0][r], s[1][r]), fmaxf(s[2][r], s[3][r]));
        #pragma unroll
        for (int off = 1; off < 16; off <<= 1)
            #pragma unroll
            for (int r = 0; r < 4; r++) mx[r] = fmaxf(mx[r], __shfl_xor(mx[r], off));

        float mnew[4], fr[4];
        #pragma unroll
        for (int r = 0; r < 4; r++) {
            mnew[r] = fmaxf(mrun[r], mx[r]);
            fr[r] = exp2f((mrun[r] - mnew[r]) * cexp);
            mrun[r] = mnew[r];
        }

        float rs[4] = {0.f, 0.f, 0.f, 0.f};
        ushort_t* pb = pbuf[wid];
        #pragma unroll
        for (int nt = 0; nt < 4; nt++) {
            #pragma unroll
            for (int r = 0; r < 4; r++) {
                float p = exp2f((s[nt][r] - mnew[r]) * cexp);
                rs[r] += p;
                pb[(2 * nt + (lr >> 3)) * 128 + (4 * lg + r) * 8 + (lr & 7)] = f2bf(p);
            }
        }
        #pragma unroll
        for (int off = 1; off < 16; off <<= 1)
            #pragma unroll
            for (int r = 0; r < 4; r++) rs[r] += __shfl_xor(rs[r], off);
        #pragma unroll
        for (int r = 0; r < 4; r++) lrun[r] = lrun[r] * fr[r] + rs[r];
        #pragma unroll
        for (int dt = 0; dt < 8; dt++)
            #pragma unroll
            for (int r = 0; r < 4; r++) accO[dt][r] *= fr[r];

        // PV: A = P (from wave-private LDS), B = V (blocked layout)
        v8s pa[2];
        #pragma unroll
        for (int kk = 0; kk < 2; kk++)
            pa[kk] = *(const v8s*)(pb + (4 * kk + lg) * 128 + lr * 8);
        #pragma unroll
        for (int dt = 0; dt < 8; dt++) {
            #pragma unroll
            for (int kk = 0; kk < 2; kk++) {
                v8s vf = *(const v8s*)(vbuf + (kk * 4 + lg) * 1024 + (lr + 16 * dt) * 8);
                accO[dt] = MFMA16(pa[kk], vf, accO[dt]);
            }
        }
    }

    // epilogue
    #pragma unroll
    for (int r = 0; r < 4; r++) {
        float inv = 1.0f / lrun[r];
        float* orow = out + ((size_t)(b * 4096 + qt0 + wid * 16 + 4 * lg + r)) * 128 + lr;
        #pragma unroll
        for (int dt = 0; dt < 8; dt++) orow[dt * 16] = accO[dt][r] * inv;
    }
}

// ---------------------------------------------------------------------------
extern "C" void kernel_launch(void* const* d_in, const int* in_sizes, int n_in,
                              void* d_out, int out_size, void* d_ws, size_t ws_size,
                              hipStream_t stream) {
    const float* x  = (const float*)d_in[0];
    const float* Wq = (const float*)d_in[1];
    const float* Wk = (const float*)d_in[2];
    const float* Wv = (const float*)d_in[3];
    float* out = (float*)d_out;
    char* ws = (char*)d_ws;

    ushort_t* q  = (ushort_t*)(ws);               // 4 MB  bf16 [16384][128]
    ushort_t* kb = (ushort_t*)(ws + (4u << 20));  // 4 MB  k_blk
    ushort_t* vb = (ushort_t*)(ws + (8u << 20));  // 4 MB  v_blk
    ushort_t* WT = (ushort_t*)(ws + (12u << 20)); // 1.5MB WT bf16 [3][128][2048]

    transpose_w<<<dim3(96), dim3(256), 0, stream>>>(Wq, Wk, Wv, WT);
    proj_kernel<<<dim3(384), dim3(256), 0, stream>>>(x, WT, q, kb, vb);
    attn_kernel<<<dim3(512), dim3(128), 0, stream>>>(q, kb, vb, out);
}

// Round 2
// 163.264 us; speedup vs baseline: 1.1539x; 1.1539x over previous
//
#include <hip/hip_runtime.h>
#include <hip/hip_bf16.h>
#include <stdint.h>

typedef unsigned short ushort_t;
typedef short v8s __attribute__((ext_vector_type(8)));
typedef float f32x4 __attribute__((ext_vector_type(4)));
typedef float f32x16 __attribute__((ext_vector_type(16)));

#define MFMA16(a, b, c) __builtin_amdgcn_mfma_f32_16x16x32_bf16(a, b, c, 0, 0, 0)
#define MFMA32(a, b, c) __builtin_amdgcn_mfma_f32_32x32x16_bf16(a, b, c, 0, 0, 0)

typedef __attribute__((address_space(1))) void gvoid;
typedef __attribute__((address_space(3))) void svoid;

__device__ __forceinline__ void gld16(const void* g, void* s) {
    __builtin_amdgcn_global_load_lds((gvoid*)g, (svoid*)s, 16, 0, 0);
}

__device__ __forceinline__ ushort_t f2bf(float f) {
    union { __hip_bfloat16 b; ushort_t u; } c;
    c.b = __float2bfloat16(f);
    return c.u;
}

__device__ __forceinline__ unsigned f2bf2(float a, float b) {
    union { __hip_bfloat162 b2; unsigned u; } c;
    c.b2 = __float22bfloat162_rn(make_float2(a, b));
    return c.u;
}

// ---------------------------------------------------------------------------
// Kernel 1: transpose W [2048][128] f32 -> WT [384][2048] bf16 (q|k|v rows)
// ---------------------------------------------------------------------------
__global__ void transpose_w(const float* __restrict__ Wq, const float* __restrict__ Wk,
                            const float* __restrict__ Wv, ushort_t* __restrict__ WT) {
    __shared__ float tile[64][132];
    int bid = blockIdx.x;            // 96 = 3 weights x 32 k-blocks
    int w = bid >> 5;
    int k0 = (bid & 31) << 6;
    const float* W = (w == 0) ? Wq : ((w == 1) ? Wk : Wv);
    int tid = threadIdx.x;
    #pragma unroll
    for (int i = 0; i < 8; i++) {
        int row = i * 8 + (tid >> 5);
        int col = (tid & 31) * 4;
        float4 v = *(const float4*)(W + (size_t)(k0 + row) * 128 + col);
        tile[row][col] = v.x; tile[row][col + 1] = v.y;
        tile[row][col + 2] = v.z; tile[row][col + 3] = v.w;
    }
    __syncthreads();
    int n = tid >> 1, kh = (tid & 1) * 32;
    ushort_t* dst = WT + ((size_t)(w * 128 + n)) * 2048 + k0 + kh;
    #pragma unroll
    for (int j = 0; j < 32; j += 4) {
        union { ushort_t u[4]; uint2 v2; } pk;
        #pragma unroll
        for (int e = 0; e < 4; e++) pk.u[e] = f2bf(tile[kh + j + e][n]);
        *(uint2*)(dst + j) = pk.v2;
    }
}

// ---------------------------------------------------------------------------
// Kernel 2: fused QKV projection: x[16384][2048]f32 * WT[384][2048]bf16.
// x read ONCE. 256 blocks x 64 rows, 4 waves (16 rows each), all 384 cols.
// Outputs in MFMA-32x32-fragment-blocked layouts (per batch 524288 elems):
//   q_blk/k_blk: [tile=t/32][ks=d/16][kh=(d>>3)&1][m=t%32][j=d%8]
//   v_blk:       [cg=t/16][dt=d/32][hi=(t>>3)&1][lo=d%32][j=t%8]
// ---------------------------------------------------------------------------
__device__ __forceinline__ void proj_stage(const char* xb, const char* wt, size_t m0, int it,
                                           char* abase, char* bbase, int wid, int lane) {
    #pragma unroll
    for (int i = 0; i < 4; i++) {           // A: 16KB, pre-swizzled source
        int seg = wid * 4 + i;
        int o = seg * 1024 + lane * 16;
        int row = o >> 8;
        int col = (o & 255) ^ ((row & 7) << 5);
        gld16(xb + ((m0 + row) * 2048 + (size_t)it * 64) * 4 + col, abase + seg * 1024);
    }
    #pragma unroll
    for (int i = 0; i < 12; i++) {          // B: 48KB [384][64] bf16
        int seg = wid * 12 + i;
        int o = seg * 1024 + lane * 16;
        int row = o >> 7;
        int col = (o & 127) ^ ((row & 7) << 4);
        gld16(wt + ((size_t)row * 2048 + (size_t)it * 64) * 2 + col, bbase + seg * 1024);
    }
}

__launch_bounds__(256, 1)
__global__ void proj_kernel(const float* __restrict__ x, const ushort_t* __restrict__ WT,
                            ushort_t* __restrict__ q, ushort_t* __restrict__ kb,
                            ushort_t* __restrict__ vb) {
    __shared__ float    abuf[2][4096];    // 2 x 16KB  [64m][64k] f32 swizzled
    __shared__ ushort_t bbuf[2][24576];   // 2 x 48KB  [384n][64k] bf16 swizzled

    int mt = blockIdx.x;
    size_t m0 = (size_t)mt * 64;
    int tid = threadIdx.x, lane = tid & 63, wid = tid >> 6;
    int lg = lane >> 4, lr = lane & 15;

    f32x4 acc[24];
    #pragma unroll
    for (int i = 0; i < 24; i++) acc[i] = (f32x4){0.f, 0.f, 0.f, 0.f};

    const char* xb = (const char*)x;
    const char* wt = (const char*)WT;

    proj_stage(xb, wt, m0, 0, (char*)abuf, (char*)bbuf, wid, lane);

    for (int it = 0; it < 32; ++it) {
        int cur = it & 1;
        if (it < 31) {
            proj_stage(xb, wt, m0, it + 1,
                       (char*)abuf + (cur ^ 1) * 16384, (char*)bbuf + (cur ^ 1) * 49152,
                       wid, lane);
            asm volatile("s_waitcnt vmcnt(16)" ::: "memory");
        } else {
            asm volatile("s_waitcnt vmcnt(0)" ::: "memory");
        }
        __builtin_amdgcn_sched_barrier(0);
        __builtin_amdgcn_s_barrier();

        const char* ab = (const char*)abuf + cur * 16384;
        const char* bbp = (const char*)bbuf + cur * 49152;
        #pragma unroll
        for (int kk = 0; kk < 2; kk++) {
            int arow = wid * 16 + lr;
            int abyte = arow * 256 + ((kk * 128 + lg * 32) ^ ((arow & 7) << 5));
            const float* ap = (const float*)(ab + abyte);
            float4 x0 = *(const float4*)ap;
            float4 x1 = *(const float4*)(ap + 4);
            union { v8s v; unsigned u[4]; } pk;
            pk.u[0] = f2bf2(x0.x, x0.y);
            pk.u[1] = f2bf2(x0.z, x0.w);
            pk.u[2] = f2bf2(x1.x, x1.y);
            pk.u[3] = f2bf2(x1.z, x1.w);
            v8s af = pk.v;
            __builtin_amdgcn_s_setprio(1);
            #pragma unroll
            for (int nt = 0; nt < 24; nt++) {
                int brow = nt * 16 + lr;
                int bbyte = brow * 128 + ((kk * 64 + lg * 16) ^ ((brow & 7) << 4));
                v8s bf = *(const v8s*)(bbp + bbyte);
                acc[nt] = MFMA16(af, bf, acc[nt]);
            }
            __builtin_amdgcn_s_setprio(0);
        }
        __builtin_amdgcn_s_barrier();
    }

    // epilogue: D-frag lane holds row = 4*lg+e, col = lr within each 16x16 tile
    #pragma unroll
    for (int e = 0; e < 4; e++) {
        size_t trow = m0 + (size_t)(wid * 16 + 4 * lg + e);
        int tt = (int)(trow & 4095);
        size_t base = (size_t)(trow >> 12) * 524288;
        size_t offqk = base + (size_t)(tt >> 5) * 4096 + (size_t)((lr >> 3) & 1) * 256
                     + (size_t)(tt & 31) * 8 + (lr & 7);
        #pragma unroll
        for (int n = 0; n < 8; n++)
            q[offqk + n * 512] = f2bf(acc[n][e]);
        #pragma unroll
        for (int n = 0; n < 8; n++)
            kb[offqk + n * 512] = f2bf(acc[8 + n][e]);
        size_t offv = base + (size_t)(tt >> 4) * 2048 + (size_t)((tt >> 3) & 1) * 256 + (tt & 7);
        #pragma unroll
        for (int n = 0; n < 8; n++)
            vb[offv + (n >> 1) * 512 + (size_t)((n & 1) * 16 + lr) * 8] = f2bf(acc[16 + n][e]);
    }
}

// ---------------------------------------------------------------------------
// Kernel 3: causal flash attention, 32x32 MFMA, swapped QK^T (S^T = K·Q^T),
// O^T = V^T·P^T. 512 blocks (b,qt 32 rows) x 2 waves; waves split kv tiles by
// parity, merge at end via LDS. No LDS/barriers in the hot loop; K/V/Q frags
// read directly from L2-resident blocked layouts. Longest-first per XCD.
// ---------------------------------------------------------------------------
__device__ __forceinline__ f32x16 zero16() {
    f32x16 z;
    #pragma unroll
    for (int i = 0; i < 16; i++) z[i] = 0.f;
    return z;
}

__launch_bounds__(128, 1)
__global__ void attn_kernel(const ushort_t* __restrict__ q, const ushort_t* __restrict__ kb,
                            const ushort_t* __restrict__ vb, float* __restrict__ out) {
    __shared__ float mbuf[2][16][256];
    __shared__ float mml[2][2][64];

    int bid = blockIdx.x;
    int xcd = bid & 7, rk = bid >> 3;
    int b = xcd >> 1;                       // batch pinned to XCD pair (L2 locality)
    int qt = 127 - (2 * rk + (xcd & 1));    // longest-first
    int qt0 = qt * 32;
    int tid = threadIdx.x, lane = tid & 63, wid = tid >> 6;
    int hi = lane >> 5, lo = lane & 31;
    size_t bb = (size_t)b * 524288;
    int nt = (qt >> 1) + 1;
    const float cexp = 0.08838834764831845f * 1.4426950408889634f;  // scale*log2e

    // Q fragments (B-operand): lane holds Q[qt0+lo][ks*16+hi*8+j]
    v8s qf[8];
    {
        const ushort_t* qg = q + bb + (size_t)qt * 4096 + (size_t)lane * 8;
        #pragma unroll
        for (int ks = 0; ks < 8; ks++) qf[ks] = *(const v8s*)(qg + ks * 512);
    }

    f32x16 accO[4];
    #pragma unroll
    for (int dt = 0; dt < 4; dt++) accO[dt] = zero16();
    float mrun = -1e30f, lrun = 0.f;

    for (int t = wid; t < nt; t += 2) {
        const ushort_t* kg = kb + bb + (size_t)t * 8192 + (size_t)lane * 8;
        const ushort_t* vg = vb + bb + (size_t)t * 8192 + (size_t)lane * 8;

        // S^T = K·Q^T : two 32-kv subtiles, K-loop over d (8 steps of 16)
        f32x16 s0 = zero16(), s1 = zero16();
        __builtin_amdgcn_s_setprio(1);
        #pragma unroll
        for (int ks = 0; ks < 8; ks++) {
            v8s kf = *(const v8s*)(kg + ks * 512);
            s0 = MFMA32(kf, qf[ks], s0);
        }
        #pragma unroll
        for (int ks = 0; ks < 8; ks++) {
            v8s kf = *(const v8s*)(kg + 4096 + ks * 512);
            s1 = MFMA32(kf, qf[ks], s1);
        }
        __builtin_amdgcn_s_setprio(0);

        // V^T fragments prefetch (latency hides under softmax VALU)
        v8s vf[4][4];
        #pragma unroll
        for (int c = 0; c < 4; c++)
            #pragma unroll
            for (int dt = 0; dt < 4; dt++)
                vf[c][dt] = *(const v8s*)(vg + c * 2048 + dt * 512);

        // causal mask (diagonal tile only); lane row kv=(r&3)+8*(r>>2)+4*hi
        if (t == nt - 1) {
            int qrow = qt0 + lo;
            #pragma unroll
            for (int r = 0; r < 16; r++) {
                int kvb = t * 64 + (r & 3) + 8 * (r >> 2) + 4 * hi;
                if (kvb > qrow) s0[r] = -1e30f;
                if (kvb + 32 > qrow) s1[r] = -1e30f;
            }
        }

        // online softmax: lane owns q-row lo; only cross-lane op is xor-32
        float mx = s0[0];
        #pragma unroll
        for (int r = 1; r < 16; r++) mx = fmaxf(mx, s0[r]);
        #pragma unroll
        for (int r = 0; r < 16; r++) mx = fmaxf(mx, s1[r]);
        mx = fmaxf(mx, __shfl_xor(mx, 32));

        if (__any(mx > mrun + 62.7f)) {     // defer-max: skip rescale if growth < 8/cexp
            float mnew = fmaxf(mrun, mx);
            float fr = exp2f((mrun - mnew) * cexp);
            lrun *= fr;
            #pragma unroll
            for (int dt = 0; dt < 4; dt++)
                #pragma unroll
                for (int r = 0; r < 16; r++) accO[dt][r] *= fr;
            mrun = mnew;
        }
        float mc = mrun * cexp;
        float rs = 0.f;
        #pragma unroll
        for (int r = 0; r < 16; r++) { s0[r] = exp2f(fmaf(s0[r], cexp, -mc)); rs += s0[r]; }
        #pragma unroll
        for (int r = 0; r < 16; r++) { s1[r] = exp2f(fmaf(s1[r], cexp, -mc)); rs += s1[r]; }
        rs += __shfl_xor(rs, 32);
        lrun += rs;

        // pack P to bf16 pairs
        unsigned pk0[8], pk1[8];
        #pragma unroll
        for (int k2 = 0; k2 < 8; k2++) {
            pk0[k2] = f2bf2(s0[2 * k2], s0[2 * k2 + 1]);
            pk1[k2] = f2bf2(s1[2 * k2], s1[2 * k2 + 1]);
        }

        // PV: O^T += V^T·P^T ; P-frag per 16-kv chunk assembled via 1 shfl pair
        __builtin_amdgcn_s_setprio(1);
        #pragma unroll
        for (int c = 0; c < 4; c++) {
            unsigned a0, a1, b0, b1;
            if (c == 0) { a0 = pk0[0]; a1 = pk0[1]; b0 = pk0[2]; b1 = pk0[3]; }
            else if (c == 1) { a0 = pk0[4]; a1 = pk0[5]; b0 = pk0[6]; b1 = pk0[7]; }
            else if (c == 2) { a0 = pk1[0]; a1 = pk1[1]; b0 = pk1[2]; b1 = pk1[3]; }
            else { a0 = pk1[4]; a1 = pk1[5]; b0 = pk1[6]; b1 = pk1[7]; }
            unsigned snd0 = hi ? a0 : b0, snd1 = hi ? a1 : b1;
            unsigned rcv0 = (unsigned)__shfl_xor((int)snd0, 32);
            unsigned rcv1 = (unsigned)__shfl_xor((int)snd1, 32);
            union { unsigned u[4]; v8s v; } pf;
            pf.u[0] = hi ? rcv0 : a0;
            pf.u[1] = hi ? rcv1 : a1;
            pf.u[2] = hi ? b0 : rcv0;
            pf.u[3] = hi ? b1 : rcv1;
            #pragma unroll
            for (int dt = 0; dt < 4; dt++)
                accO[dt] = MFMA32(vf[c][dt], pf.v, accO[dt]);
        }
        __builtin_amdgcn_s_setprio(0);
    }

    // merge the two waves' partial (m, l, O^T) states
    #pragma unroll
    for (int dt = 0; dt < 4; dt++)
        #pragma unroll
        for (int a = 0; a < 4; a++) {
            f32x4 w4;
            #pragma unroll
            for (int e = 0; e < 4; e++) w4[e] = accO[dt][4 * a + e];
            *(f32x4*)&mbuf[wid][dt * 4 + a][lane * 4] = w4;
        }
    mml[wid][0][lane] = mrun;
    mml[wid][1][lane] = lrun;
    __syncthreads();

    int pw = wid ^ 1;
    float m1 = mml[pw][0][lane], l1 = mml[pw][1][lane];
    float m = fmaxf(mrun, m1);
    float f0 = exp2f((mrun - m) * cexp), f1 = exp2f((m1 - m) * cexp);
    float linv = 1.f / (lrun * f0 + l1 * f1);
    float* orow = out + ((size_t)b * 4096 + qt0 + lo) * 128;
    #pragma unroll
    for (int d2 = 0; d2 < 2; d2++) {
        f32x16 aO = wid ? accO[d2 + 2] : accO[d2];   // static-reg select (no dyn index)
        int dt = wid * 2 + d2;
        #pragma unroll
        for (int a = 0; a < 4; a++) {
            f32x4 o1 = *(f32x4*)&mbuf[pw][dt * 4 + a][lane * 4];
            float4 vv;
            vv.x = (aO[4 * a + 0] * f0 + o1[0] * f1) * linv;
            vv.y = (aO[4 * a + 1] * f0 + o1[1] * f1) * linv;
            vv.z = (aO[4 * a + 2] * f0 + o1[2] * f1) * linv;
            vv.w = (aO[4 * a + 3] * f0 + o1[3] * f1) * linv;
            *(float4*)(orow + dt * 32 + 8 * a + 4 * hi) = vv;
        }
    }
}

// ---------------------------------------------------------------------------
extern "C" void kernel_launch(void* const* d_in, const int* in_sizes, int n_in,
                              void* d_out, int out_size, void* d_ws, size_t ws_size,
                              hipStream_t stream) {
    const float* x  = (const float*)d_in[0];
    const float* Wq = (const float*)d_in[1];
    const float* Wk = (const float*)d_in[2];
    const float* Wv = (const float*)d_in[3];
    float* out = (float*)d_out;
    char* ws = (char*)d_ws;

    ushort_t* q  = (ushort_t*)(ws);               // 4 MB  q_blk
    ushort_t* kb = (ushort_t*)(ws + (4u << 20));  // 4 MB  k_blk
    ushort_t* vb = (ushort_t*)(ws + (8u << 20));  // 4 MB  v_blk
    ushort_t* WT = (ushort_t*)(ws + (12u << 20)); // 1.5MB WT bf16 [384][2048]

    transpose_w<<<dim3(96), dim3(256), 0, stream>>>(Wq, Wk, Wv, WT);
    proj_kernel<<<dim3(256), dim3(256), 0, stream>>>(x, WT, q, kb, vb);
    attn_kernel<<<dim3(512), dim3(128), 0, stream>>>(q, kb, vb, out);
}

// Round 3
// 130.592 us; speedup vs baseline: 1.4426x; 1.2502x over previous
//
#include <hip/hip_runtime.h>
#include <hip/hip_bf16.h>
#include <stdint.h>

typedef unsigned short ushort_t;
typedef short v8s __attribute__((ext_vector_type(8)));
typedef float f32x4 __attribute__((ext_vector_type(4)));
typedef float f32x16 __attribute__((ext_vector_type(16)));

#define MFMA16(a, b, c) __builtin_amdgcn_mfma_f32_16x16x32_bf16(a, b, c, 0, 0, 0)
#define MFMA32(a, b, c) __builtin_amdgcn_mfma_f32_32x32x16_bf16(a, b, c, 0, 0, 0)

typedef __attribute__((address_space(1))) void gvoid;
typedef __attribute__((address_space(3))) void svoid;

__device__ __forceinline__ void gld16(const void* g, void* s) {
    __builtin_amdgcn_global_load_lds((gvoid*)g, (svoid*)s, 16, 0, 0);
}

__device__ __forceinline__ ushort_t f2bf(float f) {
    union { __hip_bfloat16 b; ushort_t u; } c;
    c.b = __float2bfloat16(f);
    return c.u;
}

__device__ __forceinline__ unsigned f2bf2(float a, float b) {
    union { __hip_bfloat162 b2; unsigned u; } c;
    c.b2 = __float22bfloat162_rn(make_float2(a, b));
    return c.u;
}

// ---------------------------------------------------------------------------
// Kernel 1: transpose W [2048][128] f32 -> WT [384][2048] bf16 (q|k|v rows)
// ---------------------------------------------------------------------------
__global__ void transpose_w(const float* __restrict__ Wq, const float* __restrict__ Wk,
                            const float* __restrict__ Wv, ushort_t* __restrict__ WT) {
    __shared__ float tile[64][132];
    int bid = blockIdx.x;            // 96 = 3 weights x 32 k-blocks
    int w = bid >> 5;
    int k0 = (bid & 31) << 6;
    const float* W = (w == 0) ? Wq : ((w == 1) ? Wk : Wv);
    int tid = threadIdx.x;
    #pragma unroll
    for (int i = 0; i < 8; i++) {
        int row = i * 8 + (tid >> 5);
        int col = (tid & 31) * 4;
        float4 v = *(const float4*)(W + (size_t)(k0 + row) * 128 + col);
        tile[row][col] = v.x; tile[row][col + 1] = v.y;
        tile[row][col + 2] = v.z; tile[row][col + 3] = v.w;
    }
    __syncthreads();
    int n = tid >> 1, kh = (tid & 1) * 32;
    ushort_t* dst = WT + ((size_t)(w * 128 + n)) * 2048 + k0 + kh;
    #pragma unroll
    for (int j = 0; j < 32; j += 4) {
        union { ushort_t u[4]; uint2 v2; } pk;
        #pragma unroll
        for (int e = 0; e < 4; e++) pk.u[e] = f2bf(tile[kh + j + e][n]);
        *(uint2*)(dst + j) = pk.v2;
    }
}

// ---------------------------------------------------------------------------
// Kernel 2: fused QKV projection.  grid 512 = 256 mtiles(M=64) x 2 nhalves(192)
// 4 waves, wave = full M (4 mtiles) x 48 cols (3 ntiles), BK=64 (32 iters).
// A: reg-staged f32->bf16 (cvt_pk) -> LDS [64][64] bf16 dbuf (8KBx2).
// B: gld16 direct, pre-swizzled source -> LDS [192][64] bf16 dbuf (24KBx2).
// Total LDS 64 KB -> 2 blocks/CU. One barrier per iteration, counted vmcnt.
// Outputs in MFMA-32x32-fragment-blocked layouts (per batch 524288 elems):
//   q_blk/k_blk: (t>>5)*4096 + (d>>4)*512 + ((d>>3)&1)*256 + (t&31)*8 + (d&7)
//   v_blk:       (t>>4)*2048 + (d>>5)*512 + ((t>>3)&1)*256 + (d&31)*8 + (t&7)
// ---------------------------------------------------------------------------
__launch_bounds__(256, 2)
__global__ void proj_kernel(const float* __restrict__ x, const ushort_t* __restrict__ WT,
                            ushort_t* __restrict__ q, ushort_t* __restrict__ kb,
                            ushort_t* __restrict__ vb) {
    __shared__ ushort_t abuf[2][4096];    // [64 m][64 k] bf16, byte ^ ((row&7)<<4)
    __shared__ ushort_t bbuf[2][12288];   // [192 n][64 k] bf16, same swizzle

    int bid = blockIdx.x;
    int mt = bid >> 1, nh = bid & 1;
    size_t m0 = (size_t)mt * 64;
    int c0 = nh * 192;
    int tid = threadIdx.x, lane = tid & 63, wid = tid >> 6;
    int lg = lane >> 4, lr = lane & 15;

    f32x4 acc[4][3];
    #pragma unroll
    for (int m = 0; m < 4; m++)
        #pragma unroll
        for (int n = 0; n < 3; n++) acc[m][n] = (f32x4){0.f, 0.f, 0.f, 0.f};

    // A-loads: wave stages rows 16*wid..+15; lane -> row 16wid+(lane>>2),
    // f32 bytes (lane&3)*64 .. +64 of the 256B k-chunk (contiguous per lane).
    int ar = 16 * wid + (lane >> 2);
    const char* xp = (const char*)x + ((m0 + ar) * 2048 + 0) * 4 + (lane & 3) * 64;
    int aswz = (ar & 7) << 4;
    int awb0 = ar * 128 + (((lane & 3) * 32 + 0) ^ aswz);
    int awb1 = ar * 128 + (((lane & 3) * 32 + 16) ^ aswz);

    // B stage: wave's 6 segs = exactly the 48 rows it reads.
    const char* bsrc[6];
    #pragma unroll
    for (int i = 0; i < 6; i++) {
        int row = 8 * (wid * 6 + i) + (lane >> 3);
        int col = ((lane & 7) * 16) ^ ((row & 7) << 4);
        bsrc[i] = (const char*)WT + (size_t)(c0 + row) * 4096 + col;
    }

    // ---- prologue: stage it=0 ----
    f32x4 areg[4];
    #pragma unroll
    for (int c = 0; c < 4; c++) areg[c] = *(const f32x4*)(xp + c * 16);
    #pragma unroll
    for (int i = 0; i < 6; i++)
        gld16(bsrc[i], (char*)bbuf + (wid * 6 + i) * 1024);
    {
        union { unsigned u[4]; v8s v; } p0, p1;
        p0.u[0] = f2bf2(areg[0][0], areg[0][1]); p0.u[1] = f2bf2(areg[0][2], areg[0][3]);
        p0.u[2] = f2bf2(areg[1][0], areg[1][1]); p0.u[3] = f2bf2(areg[1][2], areg[1][3]);
        p1.u[0] = f2bf2(areg[2][0], areg[2][1]); p1.u[1] = f2bf2(areg[2][2], areg[2][3]);
        p1.u[2] = f2bf2(areg[3][0], areg[3][1]); p1.u[3] = f2bf2(areg[3][2], areg[3][3]);
        *(v8s*)((char*)abuf + awb0) = p0.v;
        *(v8s*)((char*)abuf + awb1) = p1.v;
    }
    asm volatile("s_waitcnt lgkmcnt(0)" ::: "memory");
    __builtin_amdgcn_s_barrier();

    for (int it = 0; it < 32; ++it) {
        int cur = it & 1;
        // own B(it) segs arrived (they are the only outstanding VMEM here)
        asm volatile("s_waitcnt vmcnt(0)" ::: "memory");
        __builtin_amdgcn_sched_barrier(0);

        if (it < 31) {
            #pragma unroll
            for (int c = 0; c < 4; c++)
                areg[c] = *(const f32x4*)(xp + (it + 1) * 256 + c * 16);
            #pragma unroll
            for (int i = 0; i < 6; i++)
                gld16(bsrc[i] + (size_t)(it + 1) * 128,
                      (char*)bbuf + (cur ^ 1) * 24576 + (wid * 6 + i) * 1024);
        }

        const char* ab = (const char*)abuf + cur * 8192;
        const char* bb = (const char*)bbuf + cur * 24576;
        #pragma unroll
        for (int kk = 0; kk < 2; kk++) {
            v8s af[4], bf[3];
            #pragma unroll
            for (int m = 0; m < 4; m++) {
                int row = m * 16 + lr;
                af[m] = *(const v8s*)(ab + row * 128 + ((kk * 64 + lg * 16) ^ ((row & 7) << 4)));
            }
            #pragma unroll
            for (int n = 0; n < 3; n++) {
                int row = wid * 48 + n * 16 + lr;
                bf[n] = *(const v8s*)(bb + row * 128 + ((kk * 64 + lg * 16) ^ ((row & 7) << 4)));
            }
            __builtin_amdgcn_s_setprio(1);
            #pragma unroll
            for (int m = 0; m < 4; m++)
                #pragma unroll
                for (int n = 0; n < 3; n++)
                    acc[m][n] = MFMA16(af[m], bf[n], acc[m][n]);
            __builtin_amdgcn_s_setprio(0);
        }

        if (it < 31) {   // cvt + write A(it+1); compiler waits areg automatically
            union { unsigned u[4]; v8s v; } p0, p1;
            p0.u[0] = f2bf2(areg[0][0], areg[0][1]); p0.u[1] = f2bf2(areg[0][2], areg[0][3]);
            p0.u[2] = f2bf2(areg[1][0], areg[1][1]); p0.u[3] = f2bf2(areg[1][2], areg[1][3]);
            p1.u[0] = f2bf2(areg[2][0], areg[2][1]); p1.u[1] = f2bf2(areg[2][2], areg[2][3]);
            p1.u[2] = f2bf2(areg[3][0], areg[3][1]); p1.u[3] = f2bf2(areg[3][2], areg[3][3]);
            *(v8s*)((char*)abuf + (cur ^ 1) * 8192 + awb0) = p0.v;
            *(v8s*)((char*)abuf + (cur ^ 1) * 8192 + awb1) = p1.v;
        }
        asm volatile("s_waitcnt lgkmcnt(0)" ::: "memory");
        __builtin_amdgcn_s_barrier();
    }

    // epilogue: D-frag lane holds row = 4*lg+e, col = lr within each 16x16 tile
    #pragma unroll
    for (int m = 0; m < 4; m++) {
        #pragma unroll
        for (int e = 0; e < 4; e++) {
            size_t row = m0 + (size_t)(m * 16 + 4 * lg + e);
            int t = (int)(row & 4095);
            size_t base = (row >> 12) * 524288;
            #pragma unroll
            for (int n = 0; n < 3; n++) {
                int col = c0 + wid * 48 + n * 16 + lr;
                int w = col >> 7, d = col & 127;
                ushort_t val = f2bf(acc[m][n][e]);
                if (w == 0)
                    q[base + (size_t)(t >> 5) * 4096 + (d >> 4) * 512 + ((d >> 3) & 1) * 256 + (t & 31) * 8 + (d & 7)] = val;
                else if (w == 1)
                    kb[base + (size_t)(t >> 5) * 4096 + (d >> 4) * 512 + ((d >> 3) & 1) * 256 + (t & 31) * 8 + (d & 7)] = val;
                else
                    vb[base + (size_t)(t >> 4) * 2048 + (d >> 5) * 512 + ((t >> 3) & 1) * 256 + (d & 31) * 8 + (t & 7)] = val;
            }
        }
    }
}

// ---------------------------------------------------------------------------
// Kernel 3: causal flash attention, 32x32 MFMA, swapped QK^T (S^T = K·Q^T),
// O^T = V^T·P^T. 512 blocks (b, qtile of 32 rows) x 4 waves; waves split KV
// tiles mod 4, merge 4 partial (m,l,O) states via LDS at the end. No LDS or
// barriers in the hot loop. Long/short qtiles interleaved for load balance.
// ---------------------------------------------------------------------------
__device__ __forceinline__ f32x16 zero16() {
    f32x16 z;
    #pragma unroll
    for (int i = 0; i < 16; i++) z[i] = 0.f;
    return z;
}

__launch_bounds__(256, 2)
__global__ void attn_kernel(const ushort_t* __restrict__ q, const ushort_t* __restrict__ kb,
                            const ushort_t* __restrict__ vb, float* __restrict__ out) {
    __shared__ float obuf[4][4][16][64];   // [srcwave][dt][r][lane]  64 KB
    __shared__ float stat[2][4][64];       // m, l per wave per lane

    int bid = blockIdx.x;
    int xcd = bid & 7, rk = bid >> 3;
    int b = xcd >> 1;                       // batch pinned to XCD pair
    int g = rk * 2 + (xcd & 1);             // 0..127
    int qt = (g & 1) ? (g >> 1) : (127 - (g >> 1));   // alternate long/short
    int qt0 = qt * 32;
    int tid = threadIdx.x, lane = tid & 63, wid = tid >> 6;
    int hi = lane >> 5, lo = lane & 31;
    size_t bb = (size_t)b * 524288;
    int nt = (qt >> 1) + 1;
    const float cexp = 0.08838834764831845f * 1.4426950408889634f;  // scale*log2e

    // Q fragments (B-operand): lane holds Q[qt0+lo][ks*16+hi*8+j]
    v8s qf[8];
    {
        const ushort_t* qg = q + bb + (size_t)qt * 4096 + (size_t)lane * 8;
        #pragma unroll
        for (int ks = 0; ks < 8; ks++) qf[ks] = *(const v8s*)(qg + ks * 512);
    }

    f32x16 accO[4];
    #pragma unroll
    for (int dt = 0; dt < 4; dt++) accO[dt] = zero16();
    float mrun = -1e30f, lrun = 0.f;

    for (int t = wid; t < nt; t += 4) {
        const ushort_t* kg = kb + bb + (size_t)t * 8192 + (size_t)lane * 8;
        const ushort_t* vg = vb + bb + (size_t)t * 8192 + (size_t)lane * 8;

        // S^T = K·Q^T : two 32-kv subtiles, K-loop over d (8 steps of 16)
        f32x16 s0 = zero16(), s1 = zero16();
        __builtin_amdgcn_s_setprio(1);
        #pragma unroll
        for (int ks = 0; ks < 8; ks++) {
            v8s kf = *(const v8s*)(kg + ks * 512);
            s0 = MFMA32(kf, qf[ks], s0);
        }
        #pragma unroll
        for (int ks = 0; ks < 8; ks++) {
            v8s kf = *(const v8s*)(kg + 4096 + ks * 512);
            s1 = MFMA32(kf, qf[ks], s1);
        }
        __builtin_amdgcn_s_setprio(0);

        // V^T fragments prefetch (latency hides under softmax VALU)
        v8s vf[4][4];
        #pragma unroll
        for (int c = 0; c < 4; c++)
            #pragma unroll
            for (int dt = 0; dt < 4; dt++)
                vf[c][dt] = *(const v8s*)(vg + c * 2048 + dt * 512);

        // causal mask (diagonal tile only); S^T row index kv=(r&3)+8*(r>>2)+4*hi
        if (t == nt - 1) {
            int qrow = qt0 + lo;
            #pragma unroll
            for (int r = 0; r < 16; r++) {
                int kvb = t * 64 + (r & 3) + 8 * (r >> 2) + 4 * hi;
                if (kvb > qrow) s0[r] = -1e30f;
                if (kvb + 32 > qrow) s1[r] = -1e30f;
            }
        }

        // online softmax: lane owns q-row lo; only cross-lane op is xor-32
        float mx = s0[0];
        #pragma unroll
        for (int r = 1; r < 16; r++) mx = fmaxf(mx, s0[r]);
        #pragma unroll
        for (int r = 0; r < 16; r++) mx = fmaxf(mx, s1[r]);
        mx = fmaxf(mx, __shfl_xor(mx, 32));

        if (__any(mx > mrun + 62.7f)) {     // defer-max: skip rescale if growth < 8/cexp
            float mnew = fmaxf(mrun, mx);
            float fr = exp2f((mrun - mnew) * cexp);
            lrun *= fr;
            #pragma unroll
            for (int dt = 0; dt < 4; dt++)
                #pragma unroll
                for (int r = 0; r < 16; r++) accO[dt][r] *= fr;
            mrun = mnew;
        }
        float mc = mrun * cexp;
        float rs = 0.f;
        #pragma unroll
        for (int r = 0; r < 16; r++) { s0[r] = exp2f(fmaf(s0[r], cexp, -mc)); rs += s0[r]; }
        #pragma unroll
        for (int r = 0; r < 16; r++) { s1[r] = exp2f(fmaf(s1[r], cexp, -mc)); rs += s1[r]; }
        rs += __shfl_xor(rs, 32);
        lrun += rs;

        // pack P to bf16 pairs
        unsigned pk0[8], pk1[8];
        #pragma unroll
        for (int k2 = 0; k2 < 8; k2++) {
            pk0[k2] = f2bf2(s0[2 * k2], s0[2 * k2 + 1]);
            pk1[k2] = f2bf2(s1[2 * k2], s1[2 * k2 + 1]);
        }

        // PV: O^T += V^T·P^T ; P-frag per 16-kv chunk assembled via 1 shfl pair
        __builtin_amdgcn_s_setprio(1);
        #pragma unroll
        for (int c = 0; c < 4; c++) {
            unsigned a0, a1, b0, b1;
            if (c == 0) { a0 = pk0[0]; a1 = pk0[1]; b0 = pk0[2]; b1 = pk0[3]; }
            else if (c == 1) { a0 = pk0[4]; a1 = pk0[5]; b0 = pk0[6]; b1 = pk0[7]; }
            else if (c == 2) { a0 = pk1[0]; a1 = pk1[1]; b0 = pk1[2]; b1 = pk1[3]; }
            else { a0 = pk1[4]; a1 = pk1[5]; b0 = pk1[6]; b1 = pk1[7]; }
            unsigned snd0 = hi ? a0 : b0, snd1 = hi ? a1 : b1;
            unsigned rcv0 = (unsigned)__shfl_xor((int)snd0, 32);
            unsigned rcv1 = (unsigned)__shfl_xor((int)snd1, 32);
            union { unsigned u[4]; v8s v; } pf;
            pf.u[0] = hi ? rcv0 : a0;
            pf.u[1] = hi ? rcv1 : a1;
            pf.u[2] = hi ? b0 : rcv0;
            pf.u[3] = hi ? b1 : rcv1;
            #pragma unroll
            for (int dt = 0; dt < 4; dt++)
                accO[dt] = MFMA32(vf[c][dt], pf.v, accO[dt]);
        }
        __builtin_amdgcn_s_setprio(0);
    }

    // ---- merge the 4 waves' partial (m, l, O^T) states ----
    #pragma unroll
    for (int dt = 0; dt < 4; dt++)
        #pragma unroll
        for (int r = 0; r < 16; r++)
            obuf[wid][dt][r][lane] = accO[dt][r];
    stat[0][wid][lane] = mrun;
    stat[1][wid][lane] = lrun;
    __syncthreads();

    float m0 = stat[0][0][lane], m1 = stat[0][1][lane];
    float m2 = stat[0][2][lane], m3 = stat[0][3][lane];
    float m = fmaxf(fmaxf(m0, m1), fmaxf(m2, m3));
    float f0 = exp2f((m0 - m) * cexp), f1 = exp2f((m1 - m) * cexp);
    float f2 = exp2f((m2 - m) * cexp), f3 = exp2f((m3 - m) * cexp);
    float lsum = f0 * stat[1][0][lane] + f1 * stat[1][1][lane]
               + f2 * stat[1][2][lane] + f3 * stat[1][3][lane];
    float linv = 1.0f / lsum;

    float o[16];
    #pragma unroll
    for (int r = 0; r < 16; r++)
        o[r] = (f0 * obuf[0][wid][r][lane] + f1 * obuf[1][wid][r][lane]
              + f2 * obuf[2][wid][r][lane] + f3 * obuf[3][wid][r][lane]) * linv;

    // wave wid owns output cols wid*32..+32; col = wid*32 + 8a + 4hi + e
    float* orow = out + ((size_t)b * 4096 + qt0 + lo) * 128 + wid * 32 + 4 * hi;
    #pragma unroll
    for (int a = 0; a < 4; a++) {
        float4 vv;
        vv.x = o[4 * a + 0]; vv.y = o[4 * a + 1];
        vv.z = o[4 * a + 2]; vv.w = o[4 * a + 3];
        *(float4*)(orow + 8 * a) = vv;
    }
}

// ---------------------------------------------------------------------------
extern "C" void kernel_launch(void* const* d_in, const int* in_sizes, int n_in,
                              void* d_out, int out_size, void* d_ws, size_t ws_size,
                              hipStream_t stream) {
    const float* x  = (const float*)d_in[0];
    const float* Wq = (const float*)d_in[1];
    const float* Wk = (const float*)d_in[2];
    const float* Wv = (const float*)d_in[3];
    float* out = (float*)d_out;
    char* ws = (char*)d_ws;

    ushort_t* q  = (ushort_t*)(ws);               // 4 MB  q_blk
    ushort_t* kb = (ushort_t*)(ws + (4u << 20));  // 4 MB  k_blk
    ushort_t* vb = (ushort_t*)(ws + (8u << 20));  // 4 MB  v_blk
    ushort_t* WT = (ushort_t*)(ws + (12u << 20)); // 1.5MB WT bf16 [384][2048]

    transpose_w<<<dim3(96), dim3(256), 0, stream>>>(Wq, Wk, Wv, WT);
    proj_kernel<<<dim3(512), dim3(256), 0, stream>>>(x, WT, q, kb, vb);
    attn_kernel<<<dim3(512), dim3(256), 0, stream>>>(q, kb, vb, out);
}